// Round 6
// baseline (364.062 us; speedup 1.0000x reference)
//
#include <hip/hip_runtime.h>
#include <hip/hip_bf16.h>

#define B_ 32
#define L_ 512
#define D_ 768
#define M_ (B_*L_)
#define NEGV (-9e15f)

typedef __hip_bfloat16 bf16;
typedef short v8s __attribute__((ext_vector_type(8)));
typedef float v4f __attribute__((ext_vector_type(4)));

static __device__ __forceinline__ unsigned short f2b(float f) {
    __hip_bfloat16 h = __float2bfloat16(f);
    return *reinterpret_cast<unsigned short*>(&h);
}

static __device__ __forceinline__ float fast_tanh(float x) {
    x = fminf(fmaxf(x, -15.f), 15.f);
    float e2 = __expf(2.f * x);
    return (e2 - 1.f) / (e2 + 1.f);
}

// async global->LDS, 16B per lane; lds dest is wave-uniform base, HW scatters lane i at base+i*16
static __device__ __forceinline__ void gl_lds16(const void* g, void* l) {
    __builtin_amdgcn_global_load_lds(
        (const __attribute__((address_space(1))) unsigned int*)g,
        (__attribute__((address_space(3))) unsigned int*)l, 16, 0, 0);
}

// ---------------- segment info: sep_pos, valid_len per batch ----------------
__global__ void k_seg(const int* ids, const int* pad_p, const int* sep_p, int* seg) {
    int b = blockIdx.x, t = threadIdx.x;
    __shared__ int red[256];
    int pad = *pad_p, sepid = *sep_p;
    int minsep = L_, vcount = 0;
    for (int l = t; l < L_; l += 256) {
        int id = ids[b*L_ + l];
        if (id == sepid && l < minsep) minsep = l;
        if (id != pad) vcount++;
    }
    red[t] = minsep; __syncthreads();
    for (int s = 128; s > 0; s >>= 1) { if (t < s) red[t] = min(red[t], red[t+s]); __syncthreads(); }
    int sepmin = red[0]; __syncthreads();
    red[t] = vcount; __syncthreads();
    for (int s = 128; s > 0; s >>= 1) { if (t < s) red[t] += red[t+s]; __syncthreads(); }
    if (t == 0) {
        int vlen = red[0];
        int fb = vlen / 2; if (fb < 1) fb = 1; if (fb > L_-2) fb = L_-2;
        int sep = (sepmin < L_) ? sepmin : fb;
        seg[b*2] = sep; seg[b*2+1] = vlen;
    }
}

// ------- plain cast of 6 weights to bf16 (row-major, no transpose) -------
__global__ __launch_bounds__(256) void k_castw6(const float* w0, const float* w1, const float* w2,
                         const float* w3, const float* w4, const float* w5,
                         bf16* __restrict__ wb6) {
    int widx = blockIdx.y;
    const float* W;
    switch (widx) { case 0: W=w0; break; case 1: W=w1; break; case 2: W=w2; break;
                    case 3: W=w3; break; case 4: W=w4; break; default: W=w5; }
    int o = blockIdx.x*256 + threadIdx.x;
    wb6[(size_t)widx*D_*D_ + o] = __float2bfloat16(W[o]);
}

// ---- bias-fold vectors: vc_h = Wk_h @ bq_h (h=sup,con,rep), u_con = Wq_con @ bk_con,
// ---- d_con = bq_con . bk_con.  One wave per output element.
__global__ void k_vecs(const float* Wk_sup, const float* bq_sup,
                       const float* Wk_con, const float* bq_con,
                       const float* Wk_rep, const float* bq_rep,
                       const float* Wq_con, const float* bk_con,
                       float* __restrict__ vecs) {
    int gw = (blockIdx.x*blockDim.x + threadIdx.x) >> 6;
    int lane = threadIdx.x & 63;
    if (gw > 3072) return;
    if (gw == 3072) {   // d_con
        float s = 0.f;
        #pragma unroll
        for (int i = 0; i < D_/64; i++) s += bq_con[lane + 64*i] * bk_con[lane + 64*i];
        #pragma unroll
        for (int m = 32; m; m >>= 1) s += __shfl_xor(s, m);
        if (lane == 0) vecs[3072] = s;
        return;
    }
    int sel = gw / D_, row = gw % D_;
    const float* Wrow; const float* bv;
    switch (sel) {
        case 0: Wrow = Wk_sup + (size_t)row*D_; bv = bq_sup; break;
        case 1: Wrow = Wk_con + (size_t)row*D_; bv = bq_con; break;
        case 2: Wrow = Wk_rep + (size_t)row*D_; bv = bq_rep; break;
        default: Wrow = Wq_con + (size_t)row*D_; bv = bk_con; break;
    }
    float s = 0.f;
    #pragma unroll
    for (int i = 0; i < D_/64; i++) s += Wrow[lane + 64*i] * bv[lane + 64*i];
    #pragma unroll
    for (int m = 32; m; m >>= 1) s += __shfl_xor(s, m);
    if (lane == 0) vecs[gw] = s;
}

// ---- fused: cast x row to bf16 + 5 per-row dots (one x read total) ----
__global__ void k_prep(const float* __restrict__ x, const float* __restrict__ Wa,
                       const float* __restrict__ ba, const float* __restrict__ vecs,
                       bf16* __restrict__ xb,
                       float* __restrict__ anom, float* __restrict__ csup,
                       float* __restrict__ ccon, float* __restrict__ crep,
                       float* __restrict__ rcon) {
    int gw = (blockIdx.x*blockDim.x + threadIdx.x) >> 6;
    int lane = threadIdx.x & 63;
    if (gw >= M_) return;
    const float* xr = x + (size_t)gw*D_;
    bf16* xbr = xb + (size_t)gw*D_;
    float sa=0.f, s0=0.f, s1=0.f, s2=0.f, s3=0.f;
    #pragma unroll
    for (int i = 0; i < D_/64; i++) {
        int o = i*64 + lane;
        float xv = xr[o];
        xbr[o] = __float2bfloat16(xv);
        sa += xv * Wa[o];
        s0 += xv * vecs[o];
        s1 += xv * vecs[768 + o];
        s2 += xv * vecs[1536 + o];
        s3 += xv * vecs[2304 + o];
    }
    #pragma unroll
    for (int m = 32; m; m >>= 1) {
        sa += __shfl_xor(sa, m); s0 += __shfl_xor(s0, m); s1 += __shfl_xor(s1, m);
        s2 += __shfl_xor(s2, m); s3 += __shfl_xor(s3, m);
    }
    if (lane == 0) {
        anom[gw] = sa + ba[0];
        csup[gw] = s0; ccon[gw] = s1; crep[gw] = s2; rcon[gw] = s3;
    }
}

// ---------------- gate: masked softmax over false segment ----------------
__global__ void k_gate(const float* __restrict__ anom, const int* __restrict__ ids,
                       const int* seg, const int* pad_p, float* __restrict__ gate) {
    int b = blockIdx.x, t = threadIdx.x;
    int sep = seg[b*2]; int pad = *pad_p;
    __shared__ float red[256];
    float a0[2]; bool f0[2];
    float mx = -__builtin_inff();
    #pragma unroll
    for (int j = 0; j < 2; j++) {
        int l = t + j*256;
        bool fm = (l < sep) && (ids[b*L_+l] != pad);
        float a = anom[b*L_+l];
        f0[j] = fm; a0[j] = a;
        if (fm) mx = fmaxf(mx, a);
    }
    red[t] = mx; __syncthreads();
    for (int s = 128; s; s >>= 1) { if (t < s) red[t] = fmaxf(red[t], red[t+s]); __syncthreads(); }
    mx = red[0]; __syncthreads();
    float e[2]; float se = 0.f;
    #pragma unroll
    for (int j = 0; j < 2; j++) { e[j] = f0[j] ? __expf(a0[j]-mx) : 0.f; se += e[j]; }
    red[t] = se; __syncthreads();
    for (int s = 128; s; s >>= 1) { if (t < s) red[t] += red[t+s]; __syncthreads(); }
    se = red[0];
    float inv = 1.f / fmaxf(se, 1e-8f);
    #pragma unroll
    for (int j = 0; j < 2; j++) { int l = t + j*256; gate[b*L_+l] = e[j]*inv; }
}

// ---- AT_h = Wk_h @ Wq_h^T  (AT[v][u] = A[u][v]) — m97 structure ----
__global__ __launch_bounds__(256) void k_wqk(const bf16* __restrict__ wb6,
                                             bf16* __restrict__ AT) {
    int h = blockIdx.z;
    const bf16* Asrc = wb6 + (size_t)(2*h+1)*D_*D_;   // Wk rows
    const bf16* Bsrc = wb6 + (size_t)(2*h)*D_*D_;     // Wq rows
    bf16* outp = AT + (size_t)h*D_*D_;
    __shared__ bf16 As[128*32];
    __shared__ bf16 Bs[128*32];
    int t = threadIdx.x;
    int wave = t >> 6, lane = t & 63;
    int quad = lane >> 4, l16 = lane & 15;
    int wm = wave >> 1, wn = wave & 1;
    int row0 = blockIdx.x * 128;
    int col0 = blockIdx.y * 128;

    v4f acc[4][4];
    #pragma unroll
    for (int i = 0; i < 4; i++)
        #pragma unroll
        for (int j = 0; j < 4; j++) acc[i][j] = (v4f){0.f,0.f,0.f,0.f};

    int srow = lane >> 2;
    int skoff = (lane & 3) * 8;
    const bf16* agp0 = Asrc + (size_t)(row0 + wave*32 + srow)*D_ + skoff;
    const bf16* agp1 = agp0 + 16*D_;
    const bf16* bgp0 = Bsrc + (size_t)(col0 + wave*32 + srow)*D_ + skoff;
    const bf16* bgp1 = bgp0 + 16*D_;
    bf16* al0 = &As[(wave*2    )*512];
    bf16* al1 = &As[(wave*2 + 1)*512];
    bf16* bl0 = &Bs[(wave*2    )*512];
    bf16* bl1 = &Bs[(wave*2 + 1)*512];

    for (int k0 = 0; k0 < D_; k0 += 32) {
        gl_lds16(agp0 + k0, al0);
        gl_lds16(agp1 + k0, al1);
        gl_lds16(bgp0 + k0, bl0);
        gl_lds16(bgp1 + k0, bl1);
        __syncthreads();
        v8s af[4], bf[4];
        #pragma unroll
        for (int i = 0; i < 4; i++)
            af[i] = *reinterpret_cast<const v8s*>(&As[(wm*64 + i*16 + l16)*32 + quad*8]);
        #pragma unroll
        for (int j = 0; j < 4; j++)
            bf[j] = *reinterpret_cast<const v8s*>(&Bs[(wn*64 + j*16 + l16)*32 + quad*8]);
        #pragma unroll
        for (int i = 0; i < 4; i++)
            #pragma unroll
            for (int j = 0; j < 4; j++)
                acc[i][j] = __builtin_amdgcn_mfma_f32_16x16x32_bf16(af[i], bf[j], acc[i][j], 0, 0, 0);
        __syncthreads();
    }
    #pragma unroll
    for (int i = 0; i < 4; i++)
        #pragma unroll
        for (int j = 0; j < 4; j++) {
            int n = col0 + wn*64 + j*16 + l16;
            #pragma unroll
            for (int r = 0; r < 4; r++) {
                int m = row0 + wm*64 + i*16 + quad*4 + r;
                outp[(size_t)m*D_ + n] = __float2bfloat16(acc[i][j][r]);
            }
        }
}

// ---- G_h[b] = xb[b] @ A_h  (only 128-row tiles with r0 < sep) ----
__global__ __launch_bounds__(256) void k_gmat(const bf16* __restrict__ xb,
                                              const bf16* __restrict__ AT,
                                              const int* __restrict__ seg,
                                              bf16* __restrict__ G) {
    int b = blockIdx.x;
    int mt = blockIdx.y / 6, nt = blockIdx.y % 6;
    int h = blockIdx.z;
    int sep = seg[b*2];
    int row0 = mt*128;
    if (row0 >= sep) return;
    const bf16* Asrc = xb + (size_t)b*L_*D_;
    const bf16* Bsrc = AT + (size_t)h*D_*D_;
    bf16* outp = G + (size_t)(h*B_ + b)*L_*D_;
    __shared__ bf16 As[128*32];
    __shared__ bf16 Bs[128*32];
    int t = threadIdx.x;
    int wave = t >> 6, lane = t & 63;
    int quad = lane >> 4, l16 = lane & 15;
    int wm = wave >> 1, wn = wave & 1;
    int col0 = nt * 128;

    v4f acc[4][4];
    #pragma unroll
    for (int i = 0; i < 4; i++)
        #pragma unroll
        for (int j = 0; j < 4; j++) acc[i][j] = (v4f){0.f,0.f,0.f,0.f};

    int srow = lane >> 2;
    int skoff = (lane & 3) * 8;
    const bf16* agp0 = Asrc + (size_t)(row0 + wave*32 + srow)*D_ + skoff;
    const bf16* agp1 = agp0 + 16*D_;
    const bf16* bgp0 = Bsrc + (size_t)(col0 + wave*32 + srow)*D_ + skoff;
    const bf16* bgp1 = bgp0 + 16*D_;
    bf16* al0 = &As[(wave*2    )*512];
    bf16* al1 = &As[(wave*2 + 1)*512];
    bf16* bl0 = &Bs[(wave*2    )*512];
    bf16* bl1 = &Bs[(wave*2 + 1)*512];

    for (int k0 = 0; k0 < D_; k0 += 32) {
        gl_lds16(agp0 + k0, al0);
        gl_lds16(agp1 + k0, al1);
        gl_lds16(bgp0 + k0, bl0);
        gl_lds16(bgp1 + k0, bl1);
        __syncthreads();
        v8s af[4], bf[4];
        #pragma unroll
        for (int i = 0; i < 4; i++)
            af[i] = *reinterpret_cast<const v8s*>(&As[(wm*64 + i*16 + l16)*32 + quad*8]);
        #pragma unroll
        for (int j = 0; j < 4; j++)
            bf[j] = *reinterpret_cast<const v8s*>(&Bs[(wn*64 + j*16 + l16)*32 + quad*8]);
        #pragma unroll
        for (int i = 0; i < 4; i++)
            #pragma unroll
            for (int j = 0; j < 4; j++)
                acc[i][j] = __builtin_amdgcn_mfma_f32_16x16x32_bf16(af[i], bf[j], acc[i][j], 0, 0, 0);
        __syncthreads();
    }
    #pragma unroll
    for (int i = 0; i < 4; i++)
        #pragma unroll
        for (int j = 0; j < 4; j++) {
            int n = col0 + wn*64 + j*16 + l16;
            #pragma unroll
            for (int r = 0; r < 4; r++) {
                int m = row0 + wm*64 + i*16 + quad*4 + r;
                outp[(size_t)m*D_ + n] = __float2bfloat16(acc[i][j][r]);
            }
        }
}

// ------ scores via G.x^T: 8 waves/block, 3 col tiles/wave, softmax + gate-reduce ----
__global__ __launch_bounds__(512) void k_score(const bf16* __restrict__ G,
                                               const bf16* __restrict__ xb,
                                               const int* __restrict__ ids,
                                               const int* __restrict__ seg,
                                               const float* __restrict__ gate,
                                               const int* pad_p,
                                               const float* __restrict__ csup,
                                               const float* __restrict__ ccon,
                                               const float* __restrict__ crep,
                                               const float* __restrict__ rcon,
                                               const float* __restrict__ vecs,
                                               float* __restrict__ w_sup,
                                               float* __restrict__ w_rep) {
    int b = blockIdx.x, rt = blockIdx.y;          // x=batch for XCD L2 affinity
    int sep = seg[b*2];
    int r0 = rt*16;
    if (r0 >= sep) return;
    int pad = *pad_p;
    int wave = threadIdx.x >> 6, lane = threadIdx.x & 63;
    int quad = lane >> 4, l16 = lane & 15;
    const float inv  = 0.03608439182435161f;      // 1/sqrt(768)
    int ct0 = (sep + 1) >> 4;                     // first tile containing cols > sep

    int tile[3]; bool act[3];
    #pragma unroll
    for (int i = 0; i < 3; i++) {
        int ctv = ct0 + wave + 8*i;
        act[i] = ctv < 32;
        tile[i] = act[i] ? ctv : 31;
    }
    int qoff = (r0 + l16)*D_ + quad*8;
    int koff[3];
    #pragma unroll
    for (int i = 0; i < 3; i++) koff[i] = (tile[i]*16 + l16)*D_ + quad*8;

    v4f S[3], C[3], R[3];
    #pragma unroll
    for (int i = 0; i < 3; i++) { S[i] = (v4f){0,0,0,0}; C[i] = (v4f){0,0,0,0}; R[i] = (v4f){0,0,0,0}; }

    const bf16* gsup = G + (size_t)(0*B_ + b)*L_*D_;
    const bf16* gcon = G + (size_t)(1*B_ + b)*L_*D_;
    const bf16* grep = G + (size_t)(2*B_ + b)*L_*D_;
    const bf16* xrow = xb + (size_t)b*L_*D_;

    for (int k0 = 0; k0 < D_; k0 += 32) {
        v8s as = *reinterpret_cast<const v8s*>(gsup + qoff + k0);
        v8s ac = *reinterpret_cast<const v8s*>(gcon + qoff + k0);
        v8s ar = *reinterpret_cast<const v8s*>(grep + qoff + k0);
        #pragma unroll
        for (int i = 0; i < 3; i++) {
            v8s kf = *reinterpret_cast<const v8s*>(xrow + koff[i] + k0);
            S[i] = __builtin_amdgcn_mfma_f32_16x16x32_bf16(as, kf, S[i], 0, 0, 0);
            C[i] = __builtin_amdgcn_mfma_f32_16x16x32_bf16(ac, kf, C[i], 0, 0, 0);
            R[i] = __builtin_amdgcn_mfma_f32_16x16x32_bf16(ar, kf, R[i], 0, 0, 0);
        }
    }

    bool opt[3];
    float cs_v[3], cc_v[3], cr_v[3];
    #pragma unroll
    for (int i = 0; i < 3; i++) {
        int c = tile[i]*16 + l16;
        opt[i] = act[i] && (c > sep) && (ids[b*L_ + c] != pad);
        cs_v[i] = csup[b*L_ + c];
        cc_v[i] = ccon[b*L_ + c];
        cr_v[i] = crep[b*L_ + c];
    }
    float rc_r[4];
    #pragma unroll
    for (int r = 0; r < 4; r++) rc_r[r] = rcon[b*L_ + r0 + quad*4 + r];
    float dcon = vecs[3072];

    // assemble final logits in S (sup) and R (rep + tanh(con))
    #pragma unroll
    for (int i = 0; i < 3; i++)
        #pragma unroll
        for (int r = 0; r < 4; r++) {
            float sl = (S[i][r] + cs_v[i]) * inv;
            float cl = fast_tanh((C[i][r] + cc_v[i] + rc_r[r] + dcon) * inv);
            float rl = (R[i][r] + cr_v[i]) * inv + cl;
            S[i][r] = sl; R[i][r] = rl;
        }

    float mxs[4], mxr[4];
    #pragma unroll
    for (int r = 0; r < 4; r++) { mxs[r] = NEGV; mxr[r] = NEGV; }
    #pragma unroll
    for (int i = 0; i < 3; i++)
        #pragma unroll
        for (int r = 0; r < 4; r++) {
            float sv = opt[i] ? S[i][r] : NEGV;
            float rv = opt[i] ? R[i][r] : NEGV;
            mxs[r] = fmaxf(mxs[r], sv);
            mxr[r] = fmaxf(mxr[r], rv);
        }
    #pragma unroll
    for (int d = 1; d < 16; d <<= 1)
        #pragma unroll
        for (int r = 0; r < 4; r++) {
            mxs[r] = fmaxf(mxs[r], __shfl_xor(mxs[r], d));
            mxr[r] = fmaxf(mxr[r], __shfl_xor(mxr[r], d));
        }
    __shared__ float redm[2][16][8];
    __shared__ float reds[2][16][8];
    if (l16 == 0)
        #pragma unroll
        for (int r = 0; r < 4; r++) {
            redm[0][quad*4+r][wave] = mxs[r];
            redm[1][quad*4+r][wave] = mxr[r];
        }
    __syncthreads();
    #pragma unroll
    for (int r = 0; r < 4; r++) {
        int row = quad*4 + r;
        float m0 = NEGV, m1 = NEGV;
        #pragma unroll
        for (int wv = 0; wv < 8; wv++) {
            m0 = fmaxf(m0, redm[0][row][wv]);
            m1 = fmaxf(m1, redm[1][row][wv]);
        }
        mxs[r] = m0; mxr[r] = m1;
    }

    float ssum[4] = {0,0,0,0}, rsum[4] = {0,0,0,0};
    #pragma unroll
    for (int i = 0; i < 3; i++)
        #pragma unroll
        for (int r = 0; r < 4; r++) {
            float es = opt[i] ? __expf(S[i][r] - mxs[r]) : 0.f;
            float er = opt[i] ? __expf(R[i][r] - mxr[r]) : 0.f;
            S[i][r] = es; R[i][r] = er;
            ssum[r] += es; rsum[r] += er;
        }
    #pragma unroll
    for (int d = 1; d < 16; d <<= 1)
        #pragma unroll
        for (int r = 0; r < 4; r++) {
            ssum[r] += __shfl_xor(ssum[r], d);
            rsum[r] += __shfl_xor(rsum[r], d);
        }
    if (l16 == 0)
        #pragma unroll
        for (int r = 0; r < 4; r++) {
            reds[0][quad*4+r][wave] = ssum[r];
            reds[1][quad*4+r][wave] = rsum[r];
        }
    __syncthreads();
    float gs_[4], gr_[4];
    #pragma unroll
    for (int r = 0; r < 4; r++) {
        int row = quad*4 + r;
        float st = 0.f, rtot = 0.f;
        #pragma unroll
        for (int wv = 0; wv < 8; wv++) { st += reds[0][row][wv]; rtot += reds[1][row][wv]; }
        float g = gate[b*L_ + r0 + row];
        gs_[r] = g / st;
        gr_[r] = g / rtot;
    }

    #pragma unroll
    for (int i = 0; i < 3; i++) {
        float cs = 0.f, cr = 0.f;
        #pragma unroll
        for (int r = 0; r < 4; r++) { cs += S[i][r]*gs_[r]; cr += R[i][r]*gr_[r]; }
        cs += __shfl_xor(cs, 16); cs += __shfl_xor(cs, 32);
        cr += __shfl_xor(cr, 16); cr += __shfl_xor(cr, 32);
        if (act[i] && quad == 0) {
            int c = tile[i]*16 + l16;
            atomicAdd(&w_sup[b*L_ + c], cs);
            atomicAdd(&w_rep[b*L_ + c], cr);
        }
    }
}

// ---- 3 gemvs over L (bf16 x): partials into fused[32][2304] via atomics --
__global__ __launch_bounds__(256) void k_fused(const bf16* __restrict__ xb,
                                               const float* __restrict__ gate,
                                               const float* __restrict__ wrep,
                                               const float* __restrict__ wsup,
                                               float* __restrict__ fused) {
    int b = blockIdx.x, ch = blockIdx.y, t = threadIdx.x;
    int l0 = ch*64;
    const bf16* xb_ = xb + (size_t)b*L_*D_;
    float a0=0,a1=0,a2=0, r0=0,r1=0,r2=0, s0=0,s1=0,s2=0;
    for (int l = l0; l < l0+64; l++) {
        float g = gate[b*L_+l], wr = wrep[b*L_+l], wv = wsup[b*L_+l];
        if (g == 0.f && wr == 0.f && wv == 0.f) continue;
        float x0 = __bfloat162float(xb_[l*D_ + t]);
        float x1 = __bfloat162float(xb_[l*D_ + t + 256]);
        float x2 = __bfloat162float(xb_[l*D_ + t + 512]);
        a0 += g*x0;  a1 += g*x1;  a2 += g*x2;
        r0 += wr*x0; r1 += wr*x1; r2 += wr*x2;
        s0 += wv*x0; s1 += wv*x1; s2 += wv*x2;
    }
    float* f = fused + (size_t)b*2304;
    atomicAdd(&f[t],        a0); atomicAdd(&f[t+256],      a1); atomicAdd(&f[t+512],      a2);
    atomicAdd(&f[768+t],    r0); atomicAdd(&f[768+t+256],  r1); atomicAdd(&f[768+t+512],  r2);
    atomicAdd(&f[1536+t],   s0); atomicAdd(&f[1536+t+256], s1); atomicAdd(&f[1536+t+512], s2);
}

// ---- MLP layer 1, split-K: 216 blocks, partial sums into h1pre via atomics ----
__global__ __launch_bounds__(256) void k_mlp1(const float* __restrict__ fused,
                                              const float* __restrict__ W1,
                                              float* __restrict__ h1pre) {
    int c0 = blockIdx.x*64, k0 = blockIdx.y*128;
    int t = threadIdx.x;
    __shared__ float fsl[32][132];
    for (int i = t*4; i < 32*128; i += 1024) {
        int b = i >> 7, k = i & 127;
        const float4 v = *reinterpret_cast<const float4*>(&fused[(size_t)b*2304 + k0 + k]);
        fsl[b][k] = v.x; fsl[b][k+1] = v.y; fsl[b][k+2] = v.z; fsl[b][k+3] = v.w;
    }
    __syncthreads();
    int c = c0 + (t & 63), bg = (t >> 6) * 8;
    float acc[8] = {0,0,0,0,0,0,0,0};
    for (int k = 0; k < 128; k++) {
        float w = W1[(size_t)(k0+k)*D_ + c];
        #pragma unroll
        for (int b = 0; b < 8; b++) acc[b] += fsl[bg+b][k] * w;
    }
    #pragma unroll
    for (int b = 0; b < 8; b++) atomicAdd(&h1pre[(size_t)(bg+b)*D_ + c], acc[b]);
}

// ---- MLP layer 2, split-K: relu(h1pre+b1) on load; partials into opre ----
__global__ __launch_bounds__(256) void k_mlp2(const float* __restrict__ h1pre,
                                              const float* __restrict__ b1,
                                              const float* __restrict__ W2,
                                              float* __restrict__ opre) {
    int c0 = blockIdx.x*64, k0 = blockIdx.y*128;
    int t = threadIdx.x;
    __shared__ float fsl[32][132];
    for (int i = t*4; i < 32*128; i += 1024) {
        int b = i >> 7, k = i & 127;
        const float4 v = *reinterpret_cast<const float4*>(&h1pre[(size_t)b*D_ + k0 + k]);
        const float4 bb = *reinterpret_cast<const float4*>(&b1[k0 + k]);
        fsl[b][k]   = fmaxf(v.x + bb.x, 0.f);
        fsl[b][k+1] = fmaxf(v.y + bb.y, 0.f);
        fsl[b][k+2] = fmaxf(v.z + bb.z, 0.f);
        fsl[b][k+3] = fmaxf(v.w + bb.w, 0.f);
    }
    __syncthreads();
    int c = c0 + (t & 63), bg = (t >> 6) * 8;
    float acc[8] = {0,0,0,0,0,0,0,0};
    for (int k = 0; k < 128; k++) {
        float w = W2[(size_t)(k0+k)*D_ + c];
        #pragma unroll
        for (int b = 0; b < 8; b++) acc[b] += fsl[bg+b][k] * w;
    }
    #pragma unroll
    for (int b = 0; b < 8; b++) atomicAdd(&opre[(size_t)(bg+b)*D_ + c], acc[b]);
}

// ---- bias2 + LayerNorm: one block per batch ----
__global__ __launch_bounds__(256) void k_ln(const float* __restrict__ opre,
                                            const float* __restrict__ b2,
                                            const float* __restrict__ lng,
                                            const float* __restrict__ lnb,
                                            float* __restrict__ out) {
    int b = blockIdx.x, t = threadIdx.x;
    __shared__ float red[256];
    float v0 = opre[(size_t)b*D_ + t]       + b2[t];
    float v1 = opre[(size_t)b*D_ + t + 256] + b2[t+256];
    float v2 = opre[(size_t)b*D_ + t + 512] + b2[t+512];
    float sum = v0+v1+v2, sq = v0*v0+v1*v1+v2*v2;
    red[t] = sum; __syncthreads();
    for (int s = 128; s; s >>= 1) { if (t < s) red[t] += red[t+s]; __syncthreads(); }
    sum = red[0]; __syncthreads();
    red[t] = sq; __syncthreads();
    for (int s = 128; s; s >>= 1) { if (t < s) red[t] += red[t+s]; __syncthreads(); }
    sq = red[0];
    float mu = sum / 768.f;
    float var = sq / 768.f - mu*mu;
    float rstd = rsqrtf(var + 1e-5f);
    out[(size_t)b*D_ + t]       = (v0-mu)*rstd*lng[t]     + lnb[t];
    out[(size_t)b*D_ + t + 256] = (v1-mu)*rstd*lng[t+256] + lnb[t+256];
    out[(size_t)b*D_ + t + 512] = (v2-mu)*rstd*lng[t+512] + lnb[t+512];
}

extern "C" void kernel_launch(void* const* d_in, const int* in_sizes, int n_in,
                              void* d_out, int out_size, void* d_ws, size_t ws_size,
                              hipStream_t stream) {
    const float* x      = (const float*)d_in[0];
    const int*   ids    = (const int*)d_in[1];
    const int*   pad_p  = (const int*)d_in[2];
    const int*   sep_p  = (const int*)d_in[3];
    const float* W_anom = (const float*)d_in[4];
    const float* b_anom = (const float*)d_in[5];
    const float* Wq_sup = (const float*)d_in[6];  const float* bq_sup = (const float*)d_in[7];
    const float* Wk_sup = (const float*)d_in[8];  const float* bk_sup = (const float*)d_in[9];
    const float* Wq_con = (const float*)d_in[10]; const float* bq_con = (const float*)d_in[11];
    const float* Wk_con = (const float*)d_in[12]; const float* bk_con = (const float*)d_in[13];
    const float* Wq_rep = (const float*)d_in[14]; const float* bq_rep = (const float*)d_in[15];
    const float* Wk_rep = (const float*)d_in[16]; const float* bk_rep = (const float*)d_in[17];
    const float* W1     = (const float*)d_in[18]; const float* b1     = (const float*)d_in[19];
    const float* W2     = (const float*)d_in[20]; const float* b2     = (const float*)d_in[21];
    const float* lng    = (const float*)d_in[22]; const float* lnb    = (const float*)d_in[23];
    float* out = (float*)d_out;

    char* w = (char*)d_ws;
    bf16*  xb    = (bf16*)(w);                      // 25,165,824
    bf16*  wb6   = (bf16*)(w + 25165824);           //  7,077,888
    bf16*  AT    = (bf16*)(w + 32243712);           //  3,538,944
    bf16*  G     = (bf16*)(w + 35782656);           // 75,497,472
    float* vecs  = (float*)(w + 111280128);         //     16,384 (vc_sup|vc_con|vc_rep|u_con|d_con)
    float* anom  = (float*)(w + 111296512);         //     65,536
    float* gate  = (float*)(w + 111362048);         //     65,536
    float* csup  = (float*)(w + 111427584);         //     65,536
    float* ccon  = (float*)(w + 111493120);         //     65,536
    float* crep  = (float*)(w + 111558656);         //     65,536
    float* rcon  = (float*)(w + 111624192);         //     65,536
    float* wsup  = (float*)(w + 111689728);         //     65,536
    float* wrep  = (float*)(w + 111755264);         //     65,536
    float* fused = (float*)(w + 111820800);         //    294,912
    float* h1pre = (float*)(w + 112115712);         //     98,304
    float* opre  = (float*)(w + 112214016);         //     98,304
    int*   seg   = (int*)  (w + 112312320);         //        256

    k_seg<<<B_, 256, 0, stream>>>(ids, pad_p, sep_p, seg);
    k_castw6<<<dim3(D_*D_/256, 6), 256, 0, stream>>>(Wq_sup, Wk_sup, Wq_con, Wk_con, Wq_rep, Wk_rep, wb6);
    k_vecs<<<769, 256, 0, stream>>>(Wk_sup, bq_sup, Wk_con, bq_con, Wk_rep, bq_rep, Wq_con, bk_con, vecs);
    k_prep<<<4096, 256, 0, stream>>>(x, W_anom, b_anom, vecs, xb, anom, csup, ccon, crep, rcon);
    k_gate<<<B_, 256, 0, stream>>>(anom, ids, seg, pad_p, gate);
    // zero: wsup + wrep + fused + h1pre + opre (contiguous, 622,592 B)
    hipMemsetAsync(wsup, 0, 622592, stream);
    k_wqk<<<dim3(6, 6, 3), 256, 0, stream>>>(wb6, AT);
    k_gmat<<<dim3(B_, 24, 3), 256, 0, stream>>>(xb, AT, seg, G);
    k_score<<<dim3(B_, 32), 512, 0, stream>>>(G, xb, ids, seg, gate, pad_p,
                                              csup, ccon, crep, rcon, vecs, wsup, wrep);
    k_fused<<<dim3(B_, 8), 256, 0, stream>>>(xb, gate, wrep, wsup, fused);
    k_mlp1<<<dim3(12, 18), 256, 0, stream>>>(fused, W1, h1pre);
    k_mlp2<<<dim3(12, 6), 256, 0, stream>>>(h1pre, b1, W2, opre);
    k_ln<<<B_, 256, 0, stream>>>(opre, b2, lng, lnb, out);
}

// Round 7
// 336.815 us; speedup vs baseline: 1.0809x; 1.0809x over previous
//
#include <hip/hip_runtime.h>
#include <hip/hip_bf16.h>

#define B_ 32
#define L_ 512
#define D_ 768
#define M_ (B_*L_)
#define GSTRIDE 776           // padded G row stride (bf16 elems): 388 words % 32 banks = 4 -> conflict-free b128
#define NEGV (-9e15f)

typedef __hip_bfloat16 bf16;
typedef short v8s __attribute__((ext_vector_type(8)));
typedef float v4f __attribute__((ext_vector_type(4)));

static __device__ __forceinline__ unsigned short f2b(float f) {
    __hip_bfloat16 h = __float2bfloat16(f);
    return *reinterpret_cast<unsigned short*>(&h);
}

static __device__ __forceinline__ float fast_tanh(float x) {
    x = fminf(fmaxf(x, -15.f), 15.f);
    float e2 = __expf(2.f * x);
    return (e2 - 1.f) / (e2 + 1.f);
}

// async global->LDS, 16B per lane; lds dest is wave-uniform base, HW scatters lane i at base+i*16
static __device__ __forceinline__ void gl_lds16(const void* g, void* l) {
    __builtin_amdgcn_global_load_lds(
        (const __attribute__((address_space(1))) unsigned int*)g,
        (__attribute__((address_space(3))) unsigned int*)l, 16, 0, 0);
}

// ---- fused setup: seg info (blocks 0..31) + weight cast (32..13855) + bias-fold vecs (13856..14624) ----
__global__ __launch_bounds__(256) void k_setup(const int* ids, const int* pad_p, const int* sep_p, int* seg,
                        const float* w0, const float* w1, const float* w2,
                        const float* w3, const float* w4, const float* w5,
                        bf16* __restrict__ wb6,
                        const float* Wk_sup, const float* bq_sup,
                        const float* Wk_con, const float* bq_con,
                        const float* Wk_rep, const float* bq_rep,
                        const float* Wq_con, const float* bk_con,
                        float* __restrict__ vecs) {
    int bid = blockIdx.x, t = threadIdx.x;
    if (bid < 32) {                       // --- seg ---
        int b = bid;
        __shared__ int red[256];
        int pad = *pad_p, sepid = *sep_p;
        int minsep = L_, vcount = 0;
        for (int l = t; l < L_; l += 256) {
            int id = ids[b*L_ + l];
            if (id == sepid && l < minsep) minsep = l;
            if (id != pad) vcount++;
        }
        red[t] = minsep; __syncthreads();
        for (int s = 128; s > 0; s >>= 1) { if (t < s) red[t] = min(red[t], red[t+s]); __syncthreads(); }
        int sepmin = red[0]; __syncthreads();
        red[t] = vcount; __syncthreads();
        for (int s = 128; s > 0; s >>= 1) { if (t < s) red[t] += red[t+s]; __syncthreads(); }
        if (t == 0) {
            int vlen = red[0];
            int fb = vlen / 2; if (fb < 1) fb = 1; if (fb > L_-2) fb = L_-2;
            int sep = (sepmin < L_) ? sepmin : fb;
            seg[b*2] = sep; seg[b*2+1] = vlen;
        }
        return;
    }
    if (bid < 32 + 13824) {               // --- cast 6 weights ---
        int e = (bid - 32)*256 + t;
        int widx = e / (D_*D_);
        int o = e % (D_*D_);
        const float* W;
        switch (widx) { case 0: W=w0; break; case 1: W=w1; break; case 2: W=w2; break;
                        case 3: W=w3; break; case 4: W=w4; break; default: W=w5; }
        wb6[e] = __float2bfloat16(W[o]);
        return;
    }
    {                                     // --- vecs: 3073 wave-dots ---
        int gw = (bid - 13856)*4 + (t >> 6);
        int lane = t & 63;
        if (gw > 3072) return;
        if (gw == 3072) {
            float s = 0.f;
            #pragma unroll
            for (int i = 0; i < D_/64; i++) s += bq_con[lane + 64*i] * bk_con[lane + 64*i];
            #pragma unroll
            for (int m = 32; m; m >>= 1) s += __shfl_xor(s, m);
            if (lane == 0) vecs[3072] = s;
            return;
        }
        int sel = gw / D_, row = gw % D_;
        const float* Wrow; const float* bv;
        switch (sel) {
            case 0: Wrow = Wk_sup + (size_t)row*D_; bv = bq_sup; break;
            case 1: Wrow = Wk_con + (size_t)row*D_; bv = bq_con; break;
            case 2: Wrow = Wk_rep + (size_t)row*D_; bv = bq_rep; break;
            default: Wrow = Wq_con + (size_t)row*D_; bv = bk_con; break;
        }
        float s = 0.f;
        #pragma unroll
        for (int i = 0; i < D_/64; i++) s += Wrow[lane + 64*i] * bv[lane + 64*i];
        #pragma unroll
        for (int m = 32; m; m >>= 1) s += __shfl_xor(s, m);
        if (lane == 0) vecs[gw] = s;
    }
}

// ---- fused: cast x row to bf16 + 5 per-row dots (one x read total) ----
__global__ void k_prep(const float* __restrict__ x, const float* __restrict__ Wa,
                       const float* __restrict__ ba, const float* __restrict__ vecs,
                       bf16* __restrict__ xb,
                       float* __restrict__ anom, float* __restrict__ csup,
                       float* __restrict__ ccon, float* __restrict__ crep,
                       float* __restrict__ rcon) {
    int gw = (blockIdx.x*blockDim.x + threadIdx.x) >> 6;
    int lane = threadIdx.x & 63;
    if (gw >= M_) return;
    const float* xr = x + (size_t)gw*D_;
    bf16* xbr = xb + (size_t)gw*D_;
    float sa=0.f, s0=0.f, s1=0.f, s2=0.f, s3=0.f;
    #pragma unroll
    for (int i = 0; i < D_/64; i++) {
        int o = i*64 + lane;
        float xv = xr[o];
        xbr[o] = __float2bfloat16(xv);
        sa += xv * Wa[o];
        s0 += xv * vecs[o];
        s1 += xv * vecs[768 + o];
        s2 += xv * vecs[1536 + o];
        s3 += xv * vecs[2304 + o];
    }
    #pragma unroll
    for (int m = 32; m; m >>= 1) {
        sa += __shfl_xor(sa, m); s0 += __shfl_xor(s0, m); s1 += __shfl_xor(s1, m);
        s2 += __shfl_xor(s2, m); s3 += __shfl_xor(s3, m);
    }
    if (lane == 0) {
        anom[gw] = sa + ba[0];
        csup[gw] = s0; ccon[gw] = s1; crep[gw] = s2; rcon[gw] = s3;
    }
}

// ---------------- gate: masked softmax over false segment ----------------
__global__ void k_gate(const float* __restrict__ anom, const int* __restrict__ ids,
                       const int* seg, const int* pad_p, float* __restrict__ gate) {
    int b = blockIdx.x, t = threadIdx.x;
    int sep = seg[b*2]; int pad = *pad_p;
    __shared__ float red[256];
    float a0[2]; bool f0[2];
    float mx = -__builtin_inff();
    #pragma unroll
    for (int j = 0; j < 2; j++) {
        int l = t + j*256;
        bool fm = (l < sep) && (ids[b*L_+l] != pad);
        float a = anom[b*L_+l];
        f0[j] = fm; a0[j] = a;
        if (fm) mx = fmaxf(mx, a);
    }
    red[t] = mx; __syncthreads();
    for (int s = 128; s; s >>= 1) { if (t < s) red[t] = fmaxf(red[t], red[t+s]); __syncthreads(); }
    mx = red[0]; __syncthreads();
    float e[2]; float se = 0.f;
    #pragma unroll
    for (int j = 0; j < 2; j++) { e[j] = f0[j] ? __expf(a0[j]-mx) : 0.f; se += e[j]; }
    red[t] = se; __syncthreads();
    for (int s = 128; s; s >>= 1) { if (t < s) red[t] += red[t+s]; __syncthreads(); }
    se = red[0];
    float inv = 1.f / fmaxf(se, 1e-8f);
    #pragma unroll
    for (int j = 0; j < 2; j++) { int l = t + j*256; gate[b*L_+l] = e[j]*inv; }
}

// ---- AT_h = Wk_h @ Wq_h^T  (AT[v][u] = A[u][v]) — m97 structure ----
__global__ __launch_bounds__(256) void k_wqk(const bf16* __restrict__ wb6,
                                             bf16* __restrict__ AT) {
    int h = blockIdx.z;
    const bf16* Asrc = wb6 + (size_t)(2*h+1)*D_*D_;   // Wk rows
    const bf16* Bsrc = wb6 + (size_t)(2*h)*D_*D_;     // Wq rows
    bf16* outp = AT + (size_t)h*D_*D_;
    __shared__ bf16 As[128*32];
    __shared__ bf16 Bs[128*32];
    int t = threadIdx.x;
    int wave = t >> 6, lane = t & 63;
    int quad = lane >> 4, l16 = lane & 15;
    int wm = wave >> 1, wn = wave & 1;
    int row0 = blockIdx.x * 128;
    int col0 = blockIdx.y * 128;

    v4f acc[4][4];
    #pragma unroll
    for (int i = 0; i < 4; i++)
        #pragma unroll
        for (int j = 0; j < 4; j++) acc[i][j] = (v4f){0.f,0.f,0.f,0.f};

    int srow = lane >> 2;
    int skoff = (lane & 3) * 8;
    const bf16* agp0 = Asrc + (size_t)(row0 + wave*32 + srow)*D_ + skoff;
    const bf16* agp1 = agp0 + 16*D_;
    const bf16* bgp0 = Bsrc + (size_t)(col0 + wave*32 + srow)*D_ + skoff;
    const bf16* bgp1 = bgp0 + 16*D_;
    bf16* al0 = &As[(wave*2    )*512];
    bf16* al1 = &As[(wave*2 + 1)*512];
    bf16* bl0 = &Bs[(wave*2    )*512];
    bf16* bl1 = &Bs[(wave*2 + 1)*512];

    for (int k0 = 0; k0 < D_; k0 += 32) {
        gl_lds16(agp0 + k0, al0);
        gl_lds16(agp1 + k0, al1);
        gl_lds16(bgp0 + k0, bl0);
        gl_lds16(bgp1 + k0, bl1);
        __syncthreads();
        v8s af[4], bf[4];
        #pragma unroll
        for (int i = 0; i < 4; i++)
            af[i] = *reinterpret_cast<const v8s*>(&As[(wm*64 + i*16 + l16)*32 + quad*8]);
        #pragma unroll
        for (int j = 0; j < 4; j++)
            bf[j] = *reinterpret_cast<const v8s*>(&Bs[(wn*64 + j*16 + l16)*32 + quad*8]);
        #pragma unroll
        for (int i = 0; i < 4; i++)
            #pragma unroll
            for (int j = 0; j < 4; j++)
                acc[i][j] = __builtin_amdgcn_mfma_f32_16x16x32_bf16(af[i], bf[j], acc[i][j], 0, 0, 0);
        __syncthreads();
    }
    #pragma unroll
    for (int i = 0; i < 4; i++)
        #pragma unroll
        for (int j = 0; j < 4; j++) {
            int n = col0 + wn*64 + j*16 + l16;
            #pragma unroll
            for (int r = 0; r < 4; r++) {
                int m = row0 + wm*64 + i*16 + quad*4 + r;
                outp[(size_t)m*D_ + n] = __float2bfloat16(acc[i][j][r]);
            }
        }
}

// ---- G_h[b] = xb[b] @ A_h  (only row tiles < sep; sep<=256 so mt in {0,1}) ----
// G written with padded row stride GSTRIDE for conflict-free LDS staging in k_score.
__global__ __launch_bounds__(256) void k_gmat(const bf16* __restrict__ xb,
                                              const bf16* __restrict__ AT,
                                              const int* __restrict__ seg,
                                              bf16* __restrict__ G) {
    int b = blockIdx.x;
    int mt = blockIdx.y / 6, nt = blockIdx.y % 6;
    int h = blockIdx.z;
    int sep = seg[b*2];
    int row0 = mt*128;
    if (row0 >= sep) return;
    const bf16* Asrc = xb + (size_t)b*L_*D_;
    const bf16* Bsrc = AT + (size_t)h*D_*D_;
    bf16* outp = G + (size_t)(h*B_ + b)*L_*GSTRIDE;
    __shared__ bf16 As[128*32];
    __shared__ bf16 Bs[128*32];
    int t = threadIdx.x;
    int wave = t >> 6, lane = t & 63;
    int quad = lane >> 4, l16 = lane & 15;
    int wm = wave >> 1, wn = wave & 1;
    int col0 = nt * 128;

    v4f acc[4][4];
    #pragma unroll
    for (int i = 0; i < 4; i++)
        #pragma unroll
        for (int j = 0; j < 4; j++) acc[i][j] = (v4f){0.f,0.f,0.f,0.f};

    int srow = lane >> 2;
    int skoff = (lane & 3) * 8;
    const bf16* agp0 = Asrc + (size_t)(row0 + wave*32 + srow)*D_ + skoff;
    const bf16* agp1 = agp0 + 16*D_;
    const bf16* bgp0 = Bsrc + (size_t)(col0 + wave*32 + srow)*D_ + skoff;
    const bf16* bgp1 = bgp0 + 16*D_;
    bf16* al0 = &As[(wave*2    )*512];
    bf16* al1 = &As[(wave*2 + 1)*512];
    bf16* bl0 = &Bs[(wave*2    )*512];
    bf16* bl1 = &Bs[(wave*2 + 1)*512];

    for (int k0 = 0; k0 < D_; k0 += 32) {
        gl_lds16(agp0 + k0, al0);
        gl_lds16(agp1 + k0, al1);
        gl_lds16(bgp0 + k0, bl0);
        gl_lds16(bgp1 + k0, bl1);
        __syncthreads();
        v8s af[4], bf[4];
        #pragma unroll
        for (int i = 0; i < 4; i++)
            af[i] = *reinterpret_cast<const v8s*>(&As[(wm*64 + i*16 + l16)*32 + quad*8]);
        #pragma unroll
        for (int j = 0; j < 4; j++)
            bf[j] = *reinterpret_cast<const v8s*>(&Bs[(wn*64 + j*16 + l16)*32 + quad*8]);
        #pragma unroll
        for (int i = 0; i < 4; i++)
            #pragma unroll
            for (int j = 0; j < 4; j++)
                acc[i][j] = __builtin_amdgcn_mfma_f32_16x16x32_bf16(af[i], bf[j], acc[i][j], 0, 0, 0);
        __syncthreads();
    }
    #pragma unroll
    for (int i = 0; i < 4; i++)
        #pragma unroll
        for (int j = 0; j < 4; j++) {
            int n = col0 + wn*64 + j*16 + l16;
            #pragma unroll
            for (int r = 0; r < 4; r++) {
                int m = row0 + wm*64 + i*16 + quad*4 + r;
                outp[(size_t)m*GSTRIDE + n] = __float2bfloat16(acc[i][j][r]);
            }
        }
}

// ------ scores via G.x^T: G row-tile staged in LDS (no cross-wave redundancy),
// ------ 4 waves, 6 col tiles/wave, 18 MFMA chains, softmax + gate-reduce ----
__global__ __launch_bounds__(256) void k_score(const bf16* __restrict__ G,
                                               const bf16* __restrict__ xb,
                                               const int* __restrict__ ids,
                                               const int* __restrict__ seg,
                                               const float* __restrict__ gate,
                                               const int* pad_p,
                                               const float* __restrict__ csup,
                                               const float* __restrict__ ccon,
                                               const float* __restrict__ crep,
                                               const float* __restrict__ rcon,
                                               const float* __restrict__ vecs,
                                               float* __restrict__ w_sup,
                                               float* __restrict__ w_rep) {
    int b = blockIdx.x, rt = blockIdx.y;          // x=batch for XCD L2 affinity
    int sep = seg[b*2];
    int r0 = rt*16;
    if (r0 >= sep) return;
    int pad = *pad_p;
    int wave = threadIdx.x >> 6, lane = threadIdx.x & 63;
    int quad = lane >> 4, l16 = lane & 15;
    const float inv  = 0.03608439182435161f;      // 1/sqrt(768)
    int ct0 = (sep + 1) >> 4;                     // first tile containing cols > sep

    // --- stage G[h][r0..r0+16][0..768) into LDS (row stride GSTRIDE=776 -> 1552B, head image 25600B) ---
    __shared__ bf16 Gs[3*12800];                  // 76,800 B
    for (int c = wave; c < 75; c += 4) {
        int h = c / 25, cc = c % 25;              // 25 chunks of 1024B per head (768B overshoot, in-bounds)
        const char* gsrc = (const char*)(G + ((size_t)(h*B_ + b)*L_ + r0)*GSTRIDE);
        gl_lds16(gsrc + cc*1024 + lane*16, (char*)Gs + h*25600 + cc*1024);
    }

    int tile[6]; bool act[6];
    #pragma unroll
    for (int i = 0; i < 6; i++) {
        int ctv = ct0 + wave + 4*i;
        act[i] = ctv < 32;
        tile[i] = act[i] ? ctv : 31;
    }
    int koff[6];
    #pragma unroll
    for (int i = 0; i < 6; i++) koff[i] = (tile[i]*16 + l16)*D_ + quad*8;

    v4f S[6], C[6], R[6];
    #pragma unroll
    for (int i = 0; i < 6; i++) { S[i] = (v4f){0,0,0,0}; C[i] = (v4f){0,0,0,0}; R[i] = (v4f){0,0,0,0}; }

    const bf16* xrow = xb + (size_t)b*L_*D_;
    int abase = l16*1552 + quad*16;               // byte offset of A-frag in a head image

    __syncthreads();                              // staging complete
    for (int k0 = 0; k0 < D_; k0 += 32) {
        int ab = abase + k0*2;
        v8s as = *reinterpret_cast<const v8s*>((const char*)Gs + ab);
        v8s ac = *reinterpret_cast<const v8s*>((const char*)Gs + 25600 + ab);
        v8s ar = *reinterpret_cast<const v8s*>((const char*)Gs + 51200 + ab);
        #pragma unroll
        for (int i = 0; i < 6; i++) {
            v8s kf = *reinterpret_cast<const v8s*>(xrow + koff[i] + k0);
            S[i] = __builtin_amdgcn_mfma_f32_16x16x32_bf16(as, kf, S[i], 0, 0, 0);
            C[i] = __builtin_amdgcn_mfma_f32_16x16x32_bf16(ac, kf, C[i], 0, 0, 0);
            R[i] = __builtin_amdgcn_mfma_f32_16x16x32_bf16(ar, kf, R[i], 0, 0, 0);
        }
    }

    bool opt[6];
    float cs_v[6], cc_v[6], cr_v[6];
    #pragma unroll
    for (int i = 0; i < 6; i++) {
        int c = tile[i]*16 + l16;
        opt[i] = act[i] && (c > sep) && (ids[b*L_ + c] != pad);
        cs_v[i] = csup[b*L_ + c];
        cc_v[i] = ccon[b*L_ + c];
        cr_v[i] = crep[b*L_ + c];
    }
    float rc_r[4];
    #pragma unroll
    for (int r = 0; r < 4; r++) rc_r[r] = rcon[b*L_ + r0 + quad*4 + r];
    float dcon = vecs[3072];

    // assemble final logits in S (sup) and R (rep + tanh(con))
    #pragma unroll
    for (int i = 0; i < 6; i++)
        #pragma unroll
        for (int r = 0; r < 4; r++) {
            float sl = (S[i][r] + cs_v[i]) * inv;
            float cl = fast_tanh((C[i][r] + cc_v[i] + rc_r[r] + dcon) * inv);
            float rl = (R[i][r] + cr_v[i]) * inv + cl;
            S[i][r] = sl; R[i][r] = rl;
        }

    float mxs[4], mxr[4];
    #pragma unroll
    for (int r = 0; r < 4; r++) { mxs[r] = NEGV; mxr[r] = NEGV; }
    #pragma unroll
    for (int i = 0; i < 6; i++)
        #pragma unroll
        for (int r = 0; r < 4; r++) {
            float sv = opt[i] ? S[i][r] : NEGV;
            float rv = opt[i] ? R[i][r] : NEGV;
            mxs[r] = fmaxf(mxs[r], sv);
            mxr[r] = fmaxf(mxr[r], rv);
        }
    #pragma unroll
    for (int d = 1; d < 16; d <<= 1)
        #pragma unroll
        for (int r = 0; r < 4; r++) {
            mxs[r] = fmaxf(mxs[r], __shfl_xor(mxs[r], d));
            mxr[r] = fmaxf(mxr[r], __shfl_xor(mxr[r], d));
        }
    __shared__ float redm[2][16][4];
    __shared__ float reds[2][16][4];
    if (l16 == 0)
        #pragma unroll
        for (int r = 0; r < 4; r++) {
            redm[0][quad*4+r][wave] = mxs[r];
            redm[1][quad*4+r][wave] = mxr[r];
        }
    __syncthreads();
    #pragma unroll
    for (int r = 0; r < 4; r++) {
        int row = quad*4 + r;
        mxs[r] = fmaxf(fmaxf(redm[0][row][0], redm[0][row][1]), fmaxf(redm[0][row][2], redm[0][row][3]));
        mxr[r] = fmaxf(fmaxf(redm[1][row][0], redm[1][row][1]), fmaxf(redm[1][row][2], redm[1][row][3]));
    }

    float ssum[4] = {0,0,0,0}, rsum[4] = {0,0,0,0};
    #pragma unroll
    for (int i = 0; i < 6; i++)
        #pragma unroll
        for (int r = 0; r < 4; r++) {
            float es = opt[i] ? __expf(S[i][r] - mxs[r]) : 0.f;
            float er = opt[i] ? __expf(R[i][r] - mxr[r]) : 0.f;
            S[i][r] = es; R[i][r] = er;
            ssum[r] += es; rsum[r] += er;
        }
    #pragma unroll
    for (int d = 1; d < 16; d <<= 1)
        #pragma unroll
        for (int r = 0; r < 4; r++) {
            ssum[r] += __shfl_xor(ssum[r], d);
            rsum[r] += __shfl_xor(rsum[r], d);
        }
    if (l16 == 0)
        #pragma unroll
        for (int r = 0; r < 4; r++) {
            reds[0][quad*4+r][wave] = ssum[r];
            reds[1][quad*4+r][wave] = rsum[r];
        }
    __syncthreads();
    float gs_[4], gr_[4];
    #pragma unroll
    for (int r = 0; r < 4; r++) {
        int row = quad*4 + r;
        float st = reds[0][row][0] + reds[0][row][1] + reds[0][row][2] + reds[0][row][3];
        float rtot = reds[1][row][0] + reds[1][row][1] + reds[1][row][2] + reds[1][row][3];
        float g = gate[b*L_ + r0 + row];
        gs_[r] = g / st;
        gr_[r] = g / rtot;
    }

    #pragma unroll
    for (int i = 0; i < 6; i++) {
        float cs = 0.f, cr = 0.f;
        #pragma unroll
        for (int r = 0; r < 4; r++) { cs += S[i][r]*gs_[r]; cr += R[i][r]*gr_[r]; }
        cs += __shfl_xor(cs, 16); cs += __shfl_xor(cs, 32);
        cr += __shfl_xor(cr, 16); cr += __shfl_xor(cr, 32);
        if (act[i] && quad == 0) {
            int c = tile[i]*16 + l16;
            atomicAdd(&w_sup[b*L_ + c], cs);
            atomicAdd(&w_rep[b*L_ + c], cr);
        }
    }
}

// ---- 3 gemvs over L (bf16 x): partials into fused[32][2304] via atomics --
__global__ __launch_bounds__(256) void k_fused(const bf16* __restrict__ xb,
                                               const float* __restrict__ gate,
                                               const float* __restrict__ wrep,
                                               const float* __restrict__ wsup,
                                               float* __restrict__ fused) {
    int b = blockIdx.x, ch = blockIdx.y, t = threadIdx.x;
    int l0 = ch*64;
    const bf16* xb_ = xb + (size_t)b*L_*D_;
    float a0=0,a1=0,a2=0, r0=0,r1=0,r2=0, s0=0,s1=0,s2=0;
    for (int l = l0; l < l0+64; l++) {
        float g = gate[b*L_+l], wr = wrep[b*L_+l], wv = wsup[b*L_+l];
        if (g == 0.f && wr == 0.f && wv == 0.f) continue;
        float x0 = __bfloat162float(xb_[l*D_ + t]);
        float x1 = __bfloat162float(xb_[l*D_ + t + 256]);
        float x2 = __bfloat162float(xb_[l*D_ + t + 512]);
        a0 += g*x0;  a1 += g*x1;  a2 += g*x2;
        r0 += wr*x0; r1 += wr*x1; r2 += wr*x2;
        s0 += wv*x0; s1 += wv*x1; s2 += wv*x2;
    }
    float* f = fused + (size_t)b*2304;
    atomicAdd(&f[t],        a0); atomicAdd(&f[t+256],      a1); atomicAdd(&f[t+512],      a2);
    atomicAdd(&f[768+t],    r0); atomicAdd(&f[768+t+256],  r1); atomicAdd(&f[768+t+512],  r2);
    atomicAdd(&f[1536+t],   s0); atomicAdd(&f[1536+t+256], s1); atomicAdd(&f[1536+t+512], s2);
}

// ---- MLP layer 1, split-K: 216 blocks, partial sums into h1pre via atomics ----
__global__ __launch_bounds__(256) void k_mlp1(const float* __restrict__ fused,
                                              const float* __restrict__ W1,
                                              float* __restrict__ h1pre) {
    int c0 = blockIdx.x*64, k0 = blockIdx.y*128;
    int t = threadIdx.x;
    __shared__ float fsl[32][132];
    for (int i = t*4; i < 32*128; i += 1024) {
        int b = i >> 7, k = i & 127;
        const float4 v = *reinterpret_cast<const float4*>(&fused[(size_t)b*2304 + k0 + k]);
        fsl[b][k] = v.x; fsl[b][k+1] = v.y; fsl[b][k+2] = v.z; fsl[b][k+3] = v.w;
    }
    __syncthreads();
    int c = c0 + (t & 63), bg = (t >> 6) * 8;
    float acc[8] = {0,0,0,0,0,0,0,0};
    for (int k = 0; k < 128; k++) {
        float w = W1[(size_t)(k0+k)*D_ + c];
        #pragma unroll
        for (int b = 0; b < 8; b++) acc[b] += fsl[bg+b][k] * w;
    }
    #pragma unroll
    for (int b = 0; b < 8; b++) atomicAdd(&h1pre[(size_t)(bg+b)*D_ + c], acc[b]);
}

// ---- MLP layer 2, split-K: relu(h1pre+b1) on load; partials into opre ----
__global__ __launch_bounds__(256) void k_mlp2(const float* __restrict__ h1pre,
                                              const float* __restrict__ b1,
                                              const float* __restrict__ W2,
                                              float* __restrict__ opre) {
    int c0 = blockIdx.x*64, k0 = blockIdx.y*128;
    int t = threadIdx.x;
    __shared__ float fsl[32][132];
    for (int i = t*4; i < 32*128; i += 1024) {
        int b = i >> 7, k = i & 127;
        const float4 v = *reinterpret_cast<const float4*>(&h1pre[(size_t)b*D_ + k0 + k]);
        const float4 bb = *reinterpret_cast<const float4*>(&b1[k0 + k]);
        fsl[b][k]   = fmaxf(v.x + bb.x, 0.f);
        fsl[b][k+1] = fmaxf(v.y + bb.y, 0.f);
        fsl[b][k+2] = fmaxf(v.z + bb.z, 0.f);
        fsl[b][k+3] = fmaxf(v.w + bb.w, 0.f);
    }
    __syncthreads();
    int c = c0 + (t & 63), bg = (t >> 6) * 8;
    float acc[8] = {0,0,0,0,0,0,0,0};
    for (int k = 0; k < 128; k++) {
        float w = W2[(size_t)(k0+k)*D_ + c];
        #pragma unroll
        for (int b = 0; b < 8; b++) acc[b] += fsl[bg+b][k] * w;
    }
    #pragma unroll
    for (int b = 0; b < 8; b++) atomicAdd(&opre[(size_t)(bg+b)*D_ + c], acc[b]);
}

// ---- bias2 + LayerNorm: one block per batch ----
__global__ __launch_bounds__(256) void k_ln(const float* __restrict__ opre,
                                            const float* __restrict__ b2,
                                            const float* __restrict__ lng,
                                            const float* __restrict__ lnb,
                                            float* __restrict__ out) {
    int b = blockIdx.x, t = threadIdx.x;
    __shared__ float red[256];
    float v0 = opre[(size_t)b*D_ + t]       + b2[t];
    float v1 = opre[(size_t)b*D_ + t + 256] + b2[t+256];
    float v2 = opre[(size_t)b*D_ + t + 512] + b2[t+512];
    float sum = v0+v1+v2, sq = v0*v0+v1*v1+v2*v2;
    red[t] = sum; __syncthreads();
    for (int s = 128; s; s >>= 1) { if (t < s) red[t] += red[t+s]; __syncthreads(); }
    sum = red[0]; __syncthreads();
    red[t] = sq; __syncthreads();
    for (int s = 128; s; s >>= 1) { if (t < s) red[t] += red[t+s]; __syncthreads(); }
    sq = red[0];
    float mu = sum / 768.f;
    float var = sq / 768.f - mu*mu;
    float rstd = rsqrtf(var + 1e-5f);
    out[(size_t)b*D_ + t]       = (v0-mu)*rstd*lng[t]     + lnb[t];
    out[(size_t)b*D_ + t + 256] = (v1-mu)*rstd*lng[t+256] + lnb[t+256];
    out[(size_t)b*D_ + t + 512] = (v2-mu)*rstd*lng[t+512] + lnb[t+512];
}

extern "C" void kernel_launch(void* const* d_in, const int* in_sizes, int n_in,
                              void* d_out, int out_size, void* d_ws, size_t ws_size,
                              hipStream_t stream) {
    const float* x      = (const float*)d_in[0];
    const int*   ids    = (const int*)d_in[1];
    const int*   pad_p  = (const int*)d_in[2];
    const int*   sep_p  = (const int*)d_in[3];
    const float* W_anom = (const float*)d_in[4];
    const float* b_anom = (const float*)d_in[5];
    const float* Wq_sup = (const float*)d_in[6];  const float* bq_sup = (const float*)d_in[7];
    const float* Wk_sup = (const float*)d_in[8];  const float* bk_sup = (const float*)d_in[9];
    const float* Wq_con = (const float*)d_in[10]; const float* bq_con = (const float*)d_in[11];
    const float* Wk_con = (const float*)d_in[12]; const float* bk_con = (const float*)d_in[13];
    const float* Wq_rep = (const float*)d_in[14]; const float* bq_rep = (const float*)d_in[15];
    const float* Wk_rep = (const float*)d_in[16]; const float* bk_rep = (const float*)d_in[17];
    const float* W1     = (const float*)d_in[18]; const float* b1     = (const float*)d_in[19];
    const float* W2     = (const float*)d_in[20]; const float* b2     = (const float*)d_in[21];
    const float* lng    = (const float*)d_in[22]; const float* lnb    = (const float*)d_in[23];
    float* out = (float*)d_out;

    char* w = (char*)d_ws;
    bf16*  xb    = (bf16*)(w);                      // 25,165,824
    bf16*  wb6   = (bf16*)(w + 25165824);           //  7,077,888
    bf16*  AT    = (bf16*)(w + 32243712);           //  3,538,944
    bf16*  G     = (bf16*)(w + 35782656);           // 76,283,904  (3*32*512*776*2)
    float* vecs  = (float*)(w + 112066560);         //     16,384
    float* anom  = (float*)(w + 112082944);         //     65,536
    float* gate  = (float*)(w + 112148480);         //     65,536
    float* csup  = (float*)(w + 112214016);         //     65,536
    float* ccon  = (float*)(w + 112279552);         //     65,536
    float* crep  = (float*)(w + 112345088);         //     65,536
    float* rcon  = (float*)(w + 112410624);         //     65,536
    float* wsup  = (float*)(w + 112476160);         //     65,536
    float* wrep  = (float*)(w + 112541696);         //     65,536
    float* fused = (float*)(w + 112607232);         //    294,912
    float* h1pre = (float*)(w + 112902144);         //     98,304
    float* opre  = (float*)(w + 113000448);         //     98,304
    int*   seg   = (int*)  (w + 113098752);         //        256

    k_setup<<<14625, 256, 0, stream>>>(ids, pad_p, sep_p, seg,
                                       Wq_sup, Wk_sup, Wq_con, Wk_con, Wq_rep, Wk_rep, wb6,
                                       Wk_sup, bq_sup, Wk_con, bq_con, Wk_rep, bq_rep, Wq_con, bk_con, vecs);
    k_prep<<<4096, 256, 0, stream>>>(x, W_anom, b_anom, vecs, xb, anom, csup, ccon, crep, rcon);
    k_gate<<<B_, 256, 0, stream>>>(anom, ids, seg, pad_p, gate);
    // zero: wsup + wrep + fused + h1pre + opre (contiguous, 622,592 B)
    hipMemsetAsync(wsup, 0, 622592, stream);
    k_wqk<<<dim3(6, 6, 3), 256, 0, stream>>>(wb6, AT);
    k_gmat<<<dim3(B_, 12, 3), 256, 0, stream>>>(xb, AT, seg, G);
    k_score<<<dim3(B_, 16), 256, 0, stream>>>(G, xb, ids, seg, gate, pad_p,
                                              csup, ccon, crep, rcon, vecs, wsup, wrep);
    k_fused<<<dim3(B_, 8), 256, 0, stream>>>(xb, gate, wrep, wsup, fused);
    k_mlp1<<<dim3(12, 18), 256, 0, stream>>>(fused, W1, h1pre);
    k_mlp2<<<dim3(12, 6), 256, 0, stream>>>(h1pre, b1, W2, opre);
    k_ln<<<B_, 256, 0, stream>>>(opre, b2, lng, lnb, out);
}